// Round 3
// baseline (507.448 us; speedup 1.0000x reference)
//
#include <hip/hip_runtime.h>

// out[N,32] = segment_sum(edge_val[e] * weight[edge_col[e], :], edge_row[e]) + bias
// R3: row-bucket binning (LDS-staged, write-coalesced) + LDS-privatized fp32
// accumulation (ds_add_f32), zero global fp atomics, one coalesced store/row.
// Record: high32 = val bits, low32 = col | (rowlocal<<17). Needs N <= 131072.
// Fallback to R1 atomic scatter if ws too small or N too big.

#define FEAT 32
#define RB 128          // rows per bucket
#define RB_BITS 7
#define MAXB 1024       // LDS table capacity for binning kernels

// ---------------- fallback (R1 baseline, known-good) ----------------
__global__ __launch_bounds__(256) void gnn_init_out(
    const float* __restrict__ bias, float* __restrict__ out, int total) {
    int i = blockIdx.x * blockDim.x + threadIdx.x;
    if (i < total) out[i] = bias[i & (FEAT - 1)];
}

__global__ __launch_bounds__(256) void gnn_scatter(
    const int* __restrict__ edge_row, const int* __restrict__ edge_col,
    const float* __restrict__ edge_val, const float* __restrict__ weight,
    float* __restrict__ out, int num_edges) {
    long long t = (long long)blockIdx.x * blockDim.x + threadIdx.x;
    int e = (int)(t >> 5);
    int f = (int)(t & (FEAT - 1));
    if (e < num_edges) {
        atomicAdd(out + edge_row[e] * FEAT + f,
                  edge_val[e] * weight[edge_col[e] * FEAT + f]);
    }
}

// ---------------- R3 pipeline ----------------

__global__ __launch_bounds__(256) void k_zero(int* __restrict__ p, int n) {
    int i = blockIdx.x * blockDim.x + threadIdx.x;
    if (i < n) p[i] = 0;
}

// Per-block LDS histogram of bucket ids, then one global atomic per bucket.
__global__ __launch_bounds__(256) void k_hist(
    const int* __restrict__ edge_row, int* __restrict__ counts,
    int num_edges, int B, int chunk) {
    __shared__ int lc[MAXB];
    for (int i = threadIdx.x; i < B; i += 256) lc[i] = 0;
    __syncthreads();
    int base = blockIdx.x * chunk;
    int end = min(base + chunk, num_edges);
    for (int i = base + threadIdx.x; i < end; i += 256)
        atomicAdd(&lc[edge_row[i] >> RB_BITS], 1);
    __syncthreads();
    for (int i = threadIdx.x; i < B; i += 256)
        if (lc[i]) atomicAdd(&counts[i], lc[i]);
}

// Single-block exclusive scan over B<=1024 bucket counts -> start[], cursor[].
__global__ __launch_bounds__(256) void k_scan(
    const int* __restrict__ counts, int* __restrict__ start,
    int* __restrict__ cursor, int B) {
    __shared__ int tsum[256];
    int b0 = threadIdx.x * 4;
    int v0 = (b0 + 0 < B) ? counts[b0 + 0] : 0;
    int v1 = (b0 + 1 < B) ? counts[b0 + 1] : 0;
    int v2 = (b0 + 2 < B) ? counts[b0 + 2] : 0;
    int v3 = (b0 + 3 < B) ? counts[b0 + 3] : 0;
    int s = v0 + v1 + v2 + v3;
    tsum[threadIdx.x] = s;
    __syncthreads();
    #pragma unroll
    for (int off = 1; off < 256; off <<= 1) {
        int t = (threadIdx.x >= off) ? tsum[threadIdx.x - off] : 0;
        __syncthreads();
        tsum[threadIdx.x] += t;
        __syncthreads();
    }
    int ex = tsum[threadIdx.x] - s;
    if (b0 + 0 < B) { start[b0 + 0] = ex; cursor[b0 + 0] = ex; } ex += v0;
    if (b0 + 1 < B) { start[b0 + 1] = ex; cursor[b0 + 1] = ex; } ex += v1;
    if (b0 + 2 < B) { start[b0 + 2] = ex; cursor[b0 + 2] = ex; } ex += v2;
    if (b0 + 3 < B) { start[b0 + 3] = ex; cursor[b0 + 3] = ex; }
}

// LDS-staged binning: count per bucket, reserve one contiguous run per
// (block,bucket) with one global atomic, then scatter records into runs.
__global__ __launch_bounds__(256) void k_bin(
    const int* __restrict__ edge_row, const int* __restrict__ edge_col,
    const float* __restrict__ edge_val, int* __restrict__ cursor,
    unsigned long long* __restrict__ buf, int num_edges, int B, int chunk) {
    __shared__ int lc[MAXB];
    __shared__ int lbase[MAXB];
    for (int i = threadIdx.x; i < B; i += 256) lc[i] = 0;
    __syncthreads();
    int base = blockIdx.x * chunk;
    int end = min(base + chunk, num_edges);
    for (int i = base + threadIdx.x; i < end; i += 256)
        atomicAdd(&lc[edge_row[i] >> RB_BITS], 1);
    __syncthreads();
    for (int i = threadIdx.x; i < B; i += 256) {
        int c = lc[i];
        if (c) lbase[i] = atomicAdd(&cursor[i], c);
        lc[i] = 0;  // becomes local cursor
    }
    __syncthreads();
    for (int i = base + threadIdx.x; i < end; i += 256) {
        int r = edge_row[i];
        int b = r >> RB_BITS;
        int off = atomicAdd(&lc[b], 1);
        unsigned long long rec =
            ((unsigned long long)__float_as_uint(edge_val[i]) << 32) |
            (unsigned int)(edge_col[i] | ((r & (RB - 1)) << 17));
        buf[lbase[b] + off] = rec;
    }
}

// One block per bucket: LDS fp32 accumulate, then coalesced writeback + bias.
__global__ __launch_bounds__(256) void k_acc(
    const unsigned long long* __restrict__ buf,
    const int* __restrict__ start, const int* __restrict__ counts,
    const float* __restrict__ weight, const float* __restrict__ bias,
    float* __restrict__ out, int N) {
    __shared__ float acc[RB * FEAT];  // 16 KB
    for (int i = threadIdx.x; i < RB * FEAT; i += 256) acc[i] = 0.f;
    __syncthreads();
    int b = blockIdx.x;
    int s = start[b];
    int c = counts[b];
    int gid = threadIdx.x >> 5;
    int f = threadIdx.x & 31;
    int i = gid;
    for (; i + 8 < c; i += 16) {  // two independent chains per group
        unsigned long long p0 = buf[s + i];
        unsigned long long p1 = buf[s + i + 8];
        unsigned int lo0 = (unsigned int)p0, lo1 = (unsigned int)p1;
        int c0 = lo0 & 0x1FFFF, c1 = lo1 & 0x1FFFF;
        int rl0 = (lo0 >> 17) & (RB - 1), rl1 = (lo1 >> 17) & (RB - 1);
        float v0 = __uint_as_float((unsigned)(p0 >> 32));
        float v1 = __uint_as_float((unsigned)(p1 >> 32));
        float w0 = weight[c0 * FEAT + f];
        float w1 = weight[c1 * FEAT + f];
        atomicAdd(&acc[rl0 * FEAT + f], v0 * w0);
        atomicAdd(&acc[rl1 * FEAT + f], v1 * w1);
    }
    for (; i < c; i += 8) {
        unsigned long long p0 = buf[s + i];
        unsigned int lo0 = (unsigned int)p0;
        int c0 = lo0 & 0x1FFFF;
        int rl0 = (lo0 >> 17) & (RB - 1);
        float v0 = __uint_as_float((unsigned)(p0 >> 32));
        atomicAdd(&acc[rl0 * FEAT + f], v0 * weight[c0 * FEAT + f]);
    }
    __syncthreads();
    int rbase = b * RB;
    float bf = bias[f];
    for (int r = gid; r < RB; r += 8) {
        int row = rbase + r;
        if (row < N) out[row * FEAT + f] = acc[r * FEAT + f] + bf;
    }
}

extern "C" void kernel_launch(void* const* d_in, const int* in_sizes, int n_in,
                              void* d_out, int out_size, void* d_ws, size_t ws_size,
                              hipStream_t stream) {
    const int*   edge_row = (const int*)d_in[0];
    const int*   edge_col = (const int*)d_in[1];
    const float* edge_val = (const float*)d_in[2];
    const float* weight   = (const float*)d_in[3];
    const float* bias     = (const float*)d_in[4];
    float* out = (float*)d_out;

    const int E = in_sizes[0];
    const int N = out_size / FEAT;
    const int B = (N + RB - 1) / RB;

    // ws layout: counts[B] | start[B] | cursor[B] | pad | buf[E] u64
    size_t buf_off = (((size_t)3 * B) * 4 + 15) & ~(size_t)15;
    size_t need = buf_off + (size_t)E * 8;

    if (ws_size < need || B > MAXB || N > (1 << 17)) {  // fallback: R1
        gnn_init_out<<<(out_size + 255) / 256, 256, 0, stream>>>(bias, out, out_size);
        long long threads = (long long)E * FEAT;
        gnn_scatter<<<(int)((threads + 255) / 256), 256, 0, stream>>>(
            edge_row, edge_col, edge_val, weight, out, E);
        return;
    }

    int* counts = (int*)d_ws;
    int* start  = counts + B;
    int* cursor = start + B;
    unsigned long long* buf = (unsigned long long*)((char*)d_ws + buf_off);

    int chunk = ((E / 96) + 256) & ~255;           // ~16.9k edges per bin block
    int bin_blocks = (E + chunk - 1) / chunk;      // ~95

    k_zero<<<(B + 255) / 256, 256, 0, stream>>>(counts, B);
    k_hist<<<bin_blocks, 256, 0, stream>>>(edge_row, counts, E, B, chunk);
    k_scan<<<1, 256, 0, stream>>>(counts, start, cursor, B);
    k_bin<<<bin_blocks, 256, 0, stream>>>(edge_row, edge_col, edge_val,
                                          cursor, buf, E, B, chunk);
    k_acc<<<B, 256, 0, stream>>>(buf, start, counts, weight, bias, out, N);
}